// Round 1
// 108.146 us; speedup vs baseline: 1.0219x; 1.0219x over previous
//
#include <hip/hip_runtime.h>
#include <stdint.h>

#define B_DIM 16384
#define T_DIM 128
#define NB 2                 // batches per rot_apply block
#define BLK (NB * T_DIM)     // 256 threads

struct U2 { uint32_t a, b; };

__host__ __device__ constexpr uint32_t rotl32c(uint32_t x, uint32_t n) {
    return (x << n) | (x >> (32u - n));
}

// JAX threefry2x32 block cipher (20 rounds), bit-exact.
__host__ __device__ constexpr U2 tf(uint32_t k0, uint32_t k1,
                                    uint32_t x0, uint32_t x1) {
    uint32_t ks2 = k0 ^ k1 ^ 0x1BD11BDAu;
    x0 += k0; x1 += k1;
#define RND(r) { x0 += x1; x1 = rotl32c(x1, r); x1 ^= x0; }
    RND(13) RND(15) RND(26) RND(6)
    x0 += k1; x1 += ks2 + 1u;
    RND(17) RND(29) RND(16) RND(24)
    x0 += ks2; x1 += k0 + 2u;
    RND(13) RND(15) RND(26) RND(6)
    x0 += k0; x1 += k1 + 3u;
    RND(17) RND(29) RND(16) RND(24)
    x0 += k1; x1 += ks2 + 4u;
    RND(13) RND(15) RND(26) RND(6)
    x0 += ks2; x1 += k0 + 5u;
#undef RND
    return U2{x0, x1};
}

// jax_threefry_partitionable=True (modern JAX default):
//   split(key, n): child i = full cipher output of tf(key; hi=0, lo=i)
//   random_bits(key, 32, (N,)): bits[i] = o0 ^ o1 of tf(key; hi=0, lo=i)
// key(42) = (0, 42); body does key,sub = split(key) -> sub = tf(key; 0, 1)
constexpr U2 SUB = tf(0u, 42u, 0u, 1u);
// k0..k3 = split(sub, 4)
constexpr U2 K0 = tf(SUB.a, SUB.b, 0u, 0u);  // ax
constexpr U2 K1 = tf(SUB.a, SUB.b, 0u, 1u);  // ay
constexpr U2 K2 = tf(SUB.a, SUB.b, 0u, 2u);  // az
constexpr U2 K3 = tf(SUB.a, SUB.b, 0u, 3u);  // mask

__device__ __forceinline__ float bits_to_uniform(uint32_t bits) {
    // jax.random.uniform: ((bits >> 9) | 0x3F800000).view(f32) - 1.0, in [0,1)
    uint32_t u = (bits >> 9) | 0x3F800000u;
    return __uint_as_float(u) - 1.0f;
}

__device__ __forceinline__ uint32_t rbits(U2 k, uint32_t i) {
    U2 o = tf(k.a, k.b, 0u, i);
    return o.a ^ o.b;
}

// Kernel A: one thread per batch b -> R[b] (3x3 row-major), written to Rf.
// 64-thread blocks spread the 256 waves across all CUs (latency-bound ALU).
__global__ __launch_bounds__(64) void build_R_kernel(float* __restrict__ Rf) {
    int b = blockIdx.x * blockDim.x + threadIdx.x;
    if (b >= B_DIM) return;

    uint32_t bx = rbits(K0, (uint32_t)b);
    uint32_t by = rbits(K1, (uint32_t)b);
    uint32_t bz = rbits(K2, (uint32_t)b);
    uint32_t bm = rbits(K3, (uint32_t)b);

    const float PI_F = 3.14159265358979323846f;
    float ax = bits_to_uniform(bx) * 2.0f * PI_F - PI_F;
    float ay = bits_to_uniform(by) * 2.0f * PI_F - PI_F;
    float az = bits_to_uniform(bz) * 2.0f * PI_F - PI_F;
    bool mask = bits_to_uniform(bm) < 0.015625f;
    if (mask) { ax = 0.0f; ay = 0.0f; az = 0.0f; }

    float sx, cx, sy, cy, sz, cz;
    sincosf(ax, &sx, &cx);
    sincosf(ay, &sy, &cy);
    sincosf(az, &sz, &cz);

    // R = Rz @ Ry @ Rx
    float r00 = cz * cy;
    float r01 = cz * sy * sx - sz * cx;
    float r02 = cz * sy * cx + sz * sx;
    float r10 = sz * cy;
    float r11 = sz * sy * sx + cz * cx;
    float r12 = sz * sy * cx - cz * sx;
    float r20 = -sy;
    float r21 = cy * sx;
    float r22 = cy * cx;

    float* o = Rf + (size_t)b * 9;
    o[0] = r00; o[1] = r01; o[2] = r02;
    o[3] = r10; o[4] = r11; o[5] = r12;
    o[6] = r20; o[7] = r21; o[8] = r22;
}

// Kernel B: 256-thread block handles NB=2 batches; pos I/O staged through
// LDS so all global pos traffic is float4 (16 B/lane) instead of stride-12
// scalar dwords. LDS reads at stride-3 floats are 2-way bank-aliased only
// (free on gfx950). quat is float4-aligned already and goes direct.
__global__ __launch_bounds__(BLK) void rot_apply_kernel(
    const float* __restrict__ pos, const float* __restrict__ quat,
    const float* __restrict__ Rf, float* __restrict__ pos_out,
    float* __restrict__ quat_out) {
    __shared__ float Ps[NB * T_DIM * 3];   // 3 KB pos staging (in, then out)
    __shared__ float Rs[NB * 9];

    const int t  = threadIdx.x;
    const int b0 = blockIdx.x * NB;

    if (t < NB * 9) Rs[t] = Rf[(size_t)b0 * 9 + t];

    // stage pos: NB*T*3 = 768 floats = 192 float4, threads 0..191
    const float4* pin = (const float4*)(pos + (size_t)b0 * T_DIM * 3);
    if (t < NB * T_DIM * 3 / 4) ((float4*)Ps)[t] = pin[t];
    __syncthreads();

    const int lb = t >> 7;            // local batch 0/1
    const int e  = t & (T_DIM - 1);   // element within batch
    const size_t idx = (size_t)(b0 + lb) * T_DIM + e;
    const int pofs = lb * (T_DIM * 3) + e * 3;

    const float* Rb = Rs + lb * 9;
    const float R00 = Rb[0], R01 = Rb[1], R02 = Rb[2];
    const float R10 = Rb[3], R11 = Rb[4], R12 = Rb[5];
    const float R20 = Rb[6], R21 = Rb[7], R22 = Rb[8];

    // pos_out = R @ pos
    const float px = Ps[pofs + 0], py = Ps[pofs + 1], pz = Ps[pofs + 2];
    const float ox = R00 * px + R01 * py + R02 * pz;
    const float oy = R10 * px + R11 * py + R12 * pz;
    const float oz = R20 * px + R21 * py + R22 * pz;

    // quat (xyzw) -> rotation matrix (pytorch3d quaternion_to_matrix, wxyz)
    float4 q = ((const float4*)quat)[idx];
    float qx = q.x, qy = q.y, qz = q.z, qw = q.w;
    float ss = qw * qw + qx * qx + qy * qy + qz * qz;
    float two = 2.0f / ss;
    float m00 = 1.0f - two * (qy * qy + qz * qz);
    float m01 = two * (qx * qy - qz * qw);
    float m02 = two * (qx * qz + qy * qw);
    float m10 = two * (qx * qy + qz * qw);
    float m11 = 1.0f - two * (qx * qx + qz * qz);
    float m12 = two * (qy * qz - qx * qw);
    float m20 = two * (qx * qz - qy * qw);
    float m21 = two * (qy * qz + qx * qw);
    float m22 = 1.0f - two * (qx * qx + qy * qy);

    // n = R @ m
    float n00 = R00 * m00 + R01 * m10 + R02 * m20;
    float n01 = R00 * m01 + R01 * m11 + R02 * m21;
    float n02 = R00 * m02 + R01 * m12 + R02 * m22;
    float n10 = R10 * m00 + R11 * m10 + R12 * m20;
    float n11 = R10 * m01 + R11 * m11 + R12 * m21;
    float n12 = R10 * m02 + R11 * m12 + R12 * m22;
    float n20 = R20 * m00 + R21 * m10 + R22 * m20;
    float n21 = R20 * m01 + R21 * m11 + R22 * m21;
    float n22 = R20 * m02 + R21 * m12 + R22 * m22;

    // matrix_to_quaternion (pytorch3d), returns wxyz; reorder to xyzw
    float t0 = 1.0f + n00 + n11 + n22;
    float t1 = 1.0f + n00 - n11 - n22;
    float t2 = 1.0f - n00 + n11 - n22;
    float t3 = 1.0f - n00 - n11 + n22;
    float q0 = sqrtf(fmaxf(t0, 1e-8f));
    float q1 = sqrtf(fmaxf(t1, 1e-8f));
    float q2 = sqrtf(fmaxf(t2, 1e-8f));
    float q3 = sqrtf(fmaxf(t3, 1e-8f));

    int best = 0; float bv = q0;           // jnp.argmax: first max
    if (q1 > bv) { best = 1; bv = q1; }
    if (q2 > bv) { best = 2; bv = q2; }
    if (q3 > bv) { best = 3; bv = q3; }

    float w, x, y, z;
    if (best == 0)      { w = q0 * q0;  x = n21 - n12; y = n02 - n20; z = n10 - n01; }
    else if (best == 1) { w = n21 - n12; x = q1 * q1;  y = n01 + n10; z = n02 + n20; }
    else if (best == 2) { w = n02 - n20; x = n10 + n01; y = q2 * q2;  z = n12 + n21; }
    else                { w = n10 - n01; x = n20 + n02; y = n21 + n12; z = q3 * q3;  }

    // one reciprocal + 4 muls instead of 4 IEEE divides (same denominator)
    const float inv = 1.0f / (2.0f * fmaxf(bv, 0.1f));
    float4 qo;
    qo.x = x * inv; qo.y = y * inv; qo.z = z * inv; qo.w = w * inv;
    ((float4*)quat_out)[idx] = qo;

    // write rotated pos back into this thread's OWN slots (no hazard), then
    // barrier and store the block slab as float4.
    Ps[pofs + 0] = ox; Ps[pofs + 1] = oy; Ps[pofs + 2] = oz;
    __syncthreads();
    float4* pout = (float4*)(pos_out + (size_t)b0 * T_DIM * 3);
    if (t < NB * T_DIM * 3 / 4) pout[t] = ((float4*)Ps)[t];
}

extern "C" void kernel_launch(void* const* d_in, const int* in_sizes, int n_in,
                              void* d_out, int out_size, void* d_ws, size_t ws_size,
                              hipStream_t stream) {
    const float* pos  = (const float*)d_in[0];
    const float* quat = (const float*)d_in[1];
    float* out = (float*)d_out;
    float* pos_out  = out;                                   // B*T*3
    float* quat_out = out + (size_t)B_DIM * T_DIM * 3;       // B*T*4
    float* Rf       = out + (size_t)B_DIM * T_DIM * 7;       // B*9

    build_R_kernel<<<B_DIM / 64, 64, 0, stream>>>(Rf);
    rot_apply_kernel<<<B_DIM / NB, BLK, 0, stream>>>(pos, quat, Rf, pos_out, quat_out);
}

// Round 2
// 107.991 us; speedup vs baseline: 1.0234x; 1.0014x over previous
//
#include <hip/hip_runtime.h>
#include <stdint.h>

#define B_DIM 16384
#define T_DIM 128
#define NB 2                 // batches per block
#define BLK (NB * T_DIM)     // 256 threads

struct U2 { uint32_t a, b; };

__host__ __device__ constexpr uint32_t rotl32c(uint32_t x, uint32_t n) {
    return (x << n) | (x >> (32u - n));
}

// JAX threefry2x32 block cipher (20 rounds), bit-exact.
__host__ __device__ constexpr U2 tf(uint32_t k0, uint32_t k1,
                                    uint32_t x0, uint32_t x1) {
    uint32_t ks2 = k0 ^ k1 ^ 0x1BD11BDAu;
    x0 += k0; x1 += k1;
#define RND(r) { x0 += x1; x1 = rotl32c(x1, r); x1 ^= x0; }
    RND(13) RND(15) RND(26) RND(6)
    x0 += k1; x1 += ks2 + 1u;
    RND(17) RND(29) RND(16) RND(24)
    x0 += ks2; x1 += k0 + 2u;
    RND(13) RND(15) RND(26) RND(6)
    x0 += k0; x1 += k1 + 3u;
    RND(17) RND(29) RND(16) RND(24)
    x0 += k1; x1 += ks2 + 4u;
    RND(13) RND(15) RND(26) RND(6)
    x0 += ks2; x1 += k0 + 5u;
#undef RND
    return U2{x0, x1};
}

// jax_threefry_partitionable=True (modern JAX default):
//   split(key, n): child i = full cipher output of tf(key; hi=0, lo=i)
//   random_bits(key, 32, (N,)): bits[i] = o0 ^ o1 of tf(key; hi=0, lo=i)
// key(42) = (0, 42); body does key,sub = split(key) -> sub = tf(key; 0, 1)
constexpr U2 SUB = tf(0u, 42u, 0u, 1u);
// k0..k3 = split(sub, 4)
constexpr U2 K0 = tf(SUB.a, SUB.b, 0u, 0u);  // ax
constexpr U2 K1 = tf(SUB.a, SUB.b, 0u, 1u);  // ay
constexpr U2 K2 = tf(SUB.a, SUB.b, 0u, 2u);  // az
constexpr U2 K3 = tf(SUB.a, SUB.b, 0u, 3u);  // mask

__device__ __forceinline__ float bits_to_uniform(uint32_t bits) {
    // jax.random.uniform: ((bits >> 9) | 0x3F800000).view(f32) - 1.0, in [0,1)
    uint32_t u = (bits >> 9) | 0x3F800000u;
    return __uint_as_float(u) - 1.0f;
}

__device__ __forceinline__ uint32_t rbits(U2 k, uint32_t i) {
    U2 o = tf(k.a, k.b, 0u, i);
    return o.a ^ o.b;
}

// Fused kernel: 256-thread block handles NB=2 batches.
//  - 8 threads compute the 8 threefry hashes (4 keys x 2 batches) -> LDS
//  - barrier; 2 threads do sincos + build R -> LDS Rs + global Rf
//  - barrier; all 256 threads run the rot-apply body.
// pos I/O staged through LDS as float4; quat is float4 direct; the serial
// R build hides under the HBM latency of the pos/quat loads issued first.
__global__ __launch_bounds__(BLK) void rot_fused_kernel(
    const float* __restrict__ pos, const float* __restrict__ quat,
    float* __restrict__ pos_out, float* __restrict__ quat_out,
    float* __restrict__ Rf) {
    __shared__ float   Ps[NB * T_DIM * 3];   // 3 KB pos staging (in, then out)
    __shared__ float   Rs[NB * 9];
    __shared__ uint32_t Bits[NB * 4];

    const int t  = threadIdx.x;
    const int b0 = blockIdx.x * NB;
    const int lb = t >> 7;            // local batch 0/1
    const int e  = t & (T_DIM - 1);   // element within batch
    const size_t idx = (size_t)(b0 + lb) * T_DIM + e;

    // issue global loads first so the serial R build hides under them
    const float4 q = ((const float4*)quat)[idx];
    const float4* pin = (const float4*)(pos + (size_t)b0 * T_DIM * 3);
    if (t < NB * T_DIM * 3 / 4) ((float4*)Ps)[t] = pin[t];

    if (t < NB * 4) {                 // 8 threads: one threefry hash each
        const int ki = t & 3;
        const U2 k = (ki == 0) ? K0 : (ki == 1) ? K1 : (ki == 2) ? K2 : K3;
        Bits[t] = rbits(k, (uint32_t)(b0 + (t >> 2)));
    }
    __syncthreads();

    if (t < NB) {                     // 2 threads: build R for batch b0+t
        const float PI_F = 3.14159265358979323846f;
        float ax = bits_to_uniform(Bits[t * 4 + 0]) * 2.0f * PI_F - PI_F;
        float ay = bits_to_uniform(Bits[t * 4 + 1]) * 2.0f * PI_F - PI_F;
        float az = bits_to_uniform(Bits[t * 4 + 2]) * 2.0f * PI_F - PI_F;
        bool mask = bits_to_uniform(Bits[t * 4 + 3]) < 0.015625f;
        if (mask) { ax = 0.0f; ay = 0.0f; az = 0.0f; }

        float sx, cx, sy, cy, sz, cz;
        sincosf(ax, &sx, &cx);
        sincosf(ay, &sy, &cy);
        sincosf(az, &sz, &cz);

        // R = Rz @ Ry @ Rx
        float r[9];
        r[0] = cz * cy;
        r[1] = cz * sy * sx - sz * cx;
        r[2] = cz * sy * cx + sz * sx;
        r[3] = sz * cy;
        r[4] = sz * sy * sx + cz * cx;
        r[5] = sz * sy * cx - cz * sx;
        r[6] = -sy;
        r[7] = cy * sx;
        r[8] = cy * cx;

        float* rs = Rs + t * 9;
        float* ro = Rf + (size_t)(b0 + t) * 9;
        #pragma unroll
        for (int i = 0; i < 9; ++i) { rs[i] = r[i]; ro[i] = r[i]; }
    }
    __syncthreads();

    const int pofs = lb * (T_DIM * 3) + e * 3;
    const float* Rb = Rs + lb * 9;
    const float R00 = Rb[0], R01 = Rb[1], R02 = Rb[2];
    const float R10 = Rb[3], R11 = Rb[4], R12 = Rb[5];
    const float R20 = Rb[6], R21 = Rb[7], R22 = Rb[8];

    // pos_out = R @ pos
    const float px = Ps[pofs + 0], py = Ps[pofs + 1], pz = Ps[pofs + 2];
    const float ox = R00 * px + R01 * py + R02 * pz;
    const float oy = R10 * px + R11 * py + R12 * pz;
    const float oz = R20 * px + R21 * py + R22 * pz;

    // quat (xyzw) -> rotation matrix (pytorch3d quaternion_to_matrix, wxyz)
    float qx = q.x, qy = q.y, qz = q.z, qw = q.w;
    float ss = qw * qw + qx * qx + qy * qy + qz * qz;
    float two = 2.0f / ss;
    float m00 = 1.0f - two * (qy * qy + qz * qz);
    float m01 = two * (qx * qy - qz * qw);
    float m02 = two * (qx * qz + qy * qw);
    float m10 = two * (qx * qy + qz * qw);
    float m11 = 1.0f - two * (qx * qx + qz * qz);
    float m12 = two * (qy * qz - qx * qw);
    float m20 = two * (qx * qz - qy * qw);
    float m21 = two * (qy * qz + qx * qw);
    float m22 = 1.0f - two * (qx * qx + qy * qy);

    // n = R @ m
    float n00 = R00 * m00 + R01 * m10 + R02 * m20;
    float n01 = R00 * m01 + R01 * m11 + R02 * m21;
    float n02 = R00 * m02 + R01 * m12 + R02 * m22;
    float n10 = R10 * m00 + R11 * m10 + R12 * m20;
    float n11 = R10 * m01 + R11 * m11 + R12 * m21;
    float n12 = R10 * m02 + R11 * m12 + R12 * m22;
    float n20 = R20 * m00 + R21 * m10 + R22 * m20;
    float n21 = R20 * m01 + R21 * m11 + R22 * m21;
    float n22 = R20 * m02 + R21 * m12 + R22 * m22;

    // matrix_to_quaternion (pytorch3d), returns wxyz; reorder to xyzw
    float t0 = 1.0f + n00 + n11 + n22;
    float t1 = 1.0f + n00 - n11 - n22;
    float t2 = 1.0f - n00 + n11 - n22;
    float t3 = 1.0f - n00 - n11 + n22;
    float q0 = sqrtf(fmaxf(t0, 1e-8f));
    float q1 = sqrtf(fmaxf(t1, 1e-8f));
    float q2 = sqrtf(fmaxf(t2, 1e-8f));
    float q3 = sqrtf(fmaxf(t3, 1e-8f));

    int best = 0; float bv = q0;           // jnp.argmax: first max
    if (q1 > bv) { best = 1; bv = q1; }
    if (q2 > bv) { best = 2; bv = q2; }
    if (q3 > bv) { best = 3; bv = q3; }

    float w, x, y, z;
    if (best == 0)      { w = q0 * q0;  x = n21 - n12; y = n02 - n20; z = n10 - n01; }
    else if (best == 1) { w = n21 - n12; x = q1 * q1;  y = n01 + n10; z = n02 + n20; }
    else if (best == 2) { w = n02 - n20; x = n10 + n01; y = q2 * q2;  z = n12 + n21; }
    else                { w = n10 - n01; x = n20 + n02; y = n21 + n12; z = q3 * q3;  }

    // one reciprocal + 4 muls instead of 4 IEEE divides (same denominator)
    const float inv = 1.0f / (2.0f * fmaxf(bv, 0.1f));
    float4 qo;
    qo.x = x * inv; qo.y = y * inv; qo.z = z * inv; qo.w = w * inv;
    ((float4*)quat_out)[idx] = qo;

    // write rotated pos back into this thread's OWN slots (no hazard), then
    // barrier and store the block slab as float4.
    Ps[pofs + 0] = ox; Ps[pofs + 1] = oy; Ps[pofs + 2] = oz;
    __syncthreads();
    float4* pout = (float4*)(pos_out + (size_t)b0 * T_DIM * 3);
    if (t < NB * T_DIM * 3 / 4) pout[t] = ((float4*)Ps)[t];
}

extern "C" void kernel_launch(void* const* d_in, const int* in_sizes, int n_in,
                              void* d_out, int out_size, void* d_ws, size_t ws_size,
                              hipStream_t stream) {
    const float* pos  = (const float*)d_in[0];
    const float* quat = (const float*)d_in[1];
    float* out = (float*)d_out;
    float* pos_out  = out;                                   // B*T*3
    float* quat_out = out + (size_t)B_DIM * T_DIM * 3;       // B*T*4
    float* Rf       = out + (size_t)B_DIM * T_DIM * 7;       // B*9

    rot_fused_kernel<<<B_DIM / NB, BLK, 0, stream>>>(pos, quat, pos_out, quat_out, Rf);
}